// Round 10
// baseline (852.762 us; speedup 1.0000x reference)
//
#include <hip/hip_runtime.h>

#define NROWS 16384
#define KCB   16384
#define DD    64
#define BM    256
#define CSPLIT 8
#define COLS_PER_BLOCK 2048
#define TILE_COLS 128
#define NTILES 16                             // COLS_PER_BLOCK / TILE_COLS
#define NCHUNK 8                              // TILE_COLS / 16
#define CAP 2560
#define DRAIN_AT 1792
#define DELTA 0.45f
#define TILE_BYTES 32768                      // [re 16KB][im 16KB] per 128-col tile

typedef __attribute__((ext_vector_type(8))) short bf16x8;
typedef __attribute__((ext_vector_type(4))) float f32x4;

__device__ __forceinline__ unsigned pk_bf16(float lo, float hi) {
    unsigned a = __float_as_uint(lo);
    unsigned b = __float_as_uint(hi);
    a += 0x7FFFu + ((a >> 16) & 1u);   // RNE to bf16
    b += 0x7FFFu + ((b >> 16) & 1u);
    return (a >> 16) | (b & 0xFFFF0000u);
}

__device__ __forceinline__ bf16x8 mk8(unsigned a, unsigned b, unsigned c, unsigned d) {
    union { uint4 u; bf16x8 v; } x;
    x.u = make_uint4(a, b, c, d);
    return x.v;
}

// XOR swizzle within 128B rows: 16 lanes -> 8 bank-slots = 2-way (free)
__device__ __forceinline__ unsigned swz(unsigned row, unsigned byte_in_row) {
    return row * 128u + (byte_in_row ^ ((row & 7u) << 4));
}

__device__ __forceinline__ void gload_lds16(const void* g, void* l) {
    __builtin_amdgcn_global_load_lds(
        (__attribute__((address_space(1))) void*)(g),
        (__attribute__((address_space(3))) void*)(l), 16, 0, 0);
}

// fast float4 rescore (round-1 FMA order) — ONLY used AFTER the t-loop,
// where the A-fragment live range has ended (r6-proven: no spill there).
__device__ __forceinline__ void rescore_fast(
    int n, int k,
    const float* __restrict__ x_re, const float* __restrict__ x_im,
    const float* __restrict__ cb_re, const float* __restrict__ cb_im,
    unsigned long long* __restrict__ best_packed)
{
    const float4* xr = (const float4*)(x_re + (size_t)n * DD);
    const float4* xi = (const float4*)(x_im + (size_t)n * DD);
    const float4* cr = (const float4*)(cb_re + (size_t)k * DD);
    const float4* ci = (const float4*)(cb_im + (size_t)k * DD);
    float accr = 0.0f, acci = 0.0f;
#pragma unroll 4
    for (int d4 = 0; d4 < 16; ++d4) {
        float4 a = xr[d4], b = xi[d4], c = cr[d4], e = ci[d4];
        accr = fmaf(a.x, c.x, accr); accr = fmaf(b.x, e.x, accr);
        acci = fmaf(a.x, e.x, acci); acci = fmaf(-b.x, c.x, acci);
        accr = fmaf(a.y, c.y, accr); accr = fmaf(b.y, e.y, accr);
        acci = fmaf(a.y, e.y, acci); acci = fmaf(-b.y, c.y, acci);
        accr = fmaf(a.z, c.z, accr); accr = fmaf(b.z, e.z, accr);
        acci = fmaf(a.z, e.z, acci); acci = fmaf(-b.z, c.z, acci);
        accr = fmaf(a.w, c.w, accr); accr = fmaf(b.w, e.w, accr);
        acci = fmaf(a.w, e.w, acci); acci = fmaf(-b.w, c.w, acci);
    }
    float m2 = accr * accr + acci * acci;
    unsigned long long key =
        ((unsigned long long)__float_as_uint(m2) << 32) | (unsigned)(~(unsigned)k);
    atomicMax(best_packed + n, key);
}

// register-light scalar rescore — used INSIDE the t-loop (mid-sweep drain).
// Same fmaf sequence as rescore_fast -> bit-identical m2 (absmax-0 safe).
// unroll(disable): keep it a tight ~15-reg loop so the hot-loop live set
// (A fragments) is never spilled around the drain (r8/r9 lesson).
__device__ __forceinline__ void rescore_lean(
    int n, int k,
    const float* __restrict__ x_re, const float* __restrict__ x_im,
    const float* __restrict__ cb_re, const float* __restrict__ cb_im,
    unsigned long long* __restrict__ best_packed)
{
    const float* xr = x_re + (size_t)n * DD;
    const float* xi = x_im + (size_t)n * DD;
    const float* cr = cb_re + (size_t)k * DD;
    const float* ci = cb_im + (size_t)k * DD;
    float accr = 0.0f, acci = 0.0f;
#pragma clang loop unroll(disable)
    for (int d = 0; d < DD; ++d) {
        float a = xr[d], b = xi[d], c = cr[d], e = ci[d];
        accr = fmaf(a, c, accr); accr = fmaf(b, e, accr);
        acci = fmaf(a, e, acci); acci = fmaf(-b, c, acci);
    }
    float m2 = accr * accr + acci * acci;
    unsigned long long key =
        ((unsigned long long)__float_as_uint(m2) << 32) | (unsigned)(~(unsigned)k);
    atomicMax(best_packed + n, key);
}

// prep: init reductions + flags; convert codebook fp32 -> bf16 in
// INVERSE-SWIZZLED tile order (linear global_load_lds dest -> swizzled reads).
__global__ __launch_bounds__(256) void prep(
    const float* __restrict__ cb_re, const float* __restrict__ cb_im,
    uint4* __restrict__ cb_sw,
    unsigned long long* __restrict__ best_packed, int* __restrict__ flags)
{
    int id = blockIdx.x * 256 + threadIdx.x;
    if (id < NROWS) best_packed[id] = 0ull;
    if (id < 512) flags[id] = 0;
    // id in [0, 262144): [gt 0..127][arr 0..1][u 0..1023], one uint4 (16B) each
    int u   = id & 1023;
    int arr = (id >> 10) & 1;
    int gt  = id >> 11;
    int c   = u >> 3;                                  // col within tile
    int b   = ((u & 7) * 16) ^ ((c & 7) << 4);         // inverse-swizzled byte
    int col = gt * TILE_COLS + c;
    int d0  = b >> 1;                                  // bf16 element index (8-aligned)
    const float* src = arr ? cb_im : cb_re;
    const float4* p = (const float4*)(src + (size_t)col * DD + d0);
    float4 f0 = p[0], f1 = p[1];
    cb_sw[id] = make_uint4(pk_bf16(f0.x, f0.y), pk_bf16(f0.z, f0.w),
                           pk_bf16(f1.x, f1.y), pk_bf16(f1.z, f1.w));
}

__global__ __launch_bounds__(512, 2) void score_kernel(
    const float* __restrict__ x_re, const float* __restrict__ x_im,
    const float* __restrict__ cb_re, const float* __restrict__ cb_im,
    const char* __restrict__ cb_sw,
    unsigned long long* __restrict__ best_packed, int* __restrict__ flags)
{
    __shared__ char Bls[2][2][TILE_COLS * 128];   // 64 KB
    __shared__ unsigned cand[CAP];                // 10 KB
    __shared__ unsigned smax[BM];                 // 1 KB, per-row running bf16 max
    __shared__ int cand_cnt;

    const int tid  = threadIdx.x;
    const int lane = tid & 63;
    const int wid  = tid >> 6;          // 0..7 = row-group of 32
    const int row0 = blockIdx.x * BM;
    const int col0 = blockIdx.y * COLS_PER_BLOCK;
    const int bid  = blockIdx.y * gridDim.x + blockIdx.x;
    const int l15  = lane & 15;
    const int lhi  = lane >> 4;         // 0..3

    if (tid == 0) cand_cnt = 0;
    if (tid < BM) smax[tid] = 0u;

    // ---- A fragments: 32 rows/wave, {re, im}, built once in registers ----
    bf16x8 Ar[2][2], Ai[2][2];
#pragma unroll
    for (int a = 0; a < 2; ++a) {
        const int row = row0 + wid * 32 + a * 16 + l15;
        {
            const float4* pr = (const float4*)(x_re + (size_t)row * DD + lhi * 8);
            const float4* pi = (const float4*)(x_im + (size_t)row * DD + lhi * 8);
            float4 r0 = pr[0], r1 = pr[1];
            float4 i0 = pi[0], i1 = pi[1];
            Ar[a][0] = mk8(pk_bf16(r0.x, r0.y), pk_bf16(r0.z, r0.w),
                           pk_bf16(r1.x, r1.y), pk_bf16(r1.z, r1.w));
            Ai[a][0] = mk8(pk_bf16(i0.x, i0.y), pk_bf16(i0.z, i0.w),
                           pk_bf16(i1.x, i1.y), pk_bf16(i1.z, i1.w));
        }
        {
            const float4* pr = (const float4*)(x_re + (size_t)row * DD + 32 + lhi * 8);
            const float4* pi = (const float4*)(x_im + (size_t)row * DD + 32 + lhi * 8);
            float4 r0 = pr[0], r1 = pr[1];
            float4 i0 = pi[0], i1 = pi[1];
            Ar[a][1] = mk8(pk_bf16(r0.x, r0.y), pk_bf16(r0.z, r0.w),
                           pk_bf16(r1.x, r1.y), pk_bf16(r1.z, r1.w));
            Ai[a][1] = mk8(pk_bf16(i0.x, i0.y), pk_bf16(i0.z, i0.w),
                           pk_bf16(i1.x, i1.y), pk_bf16(i1.z, i1.w));
        }
    }

    float rm[2][4];                    // per-lane running max (monotone)
    float thr[2][4];                   // emission threshold, refreshed per tile
#pragma unroll
    for (int a = 0; a < 2; ++a)
#pragma unroll
        for (int r = 0; r < 4; ++r) { rm[a][r] = 0.0f; thr[a][r] = __builtin_inff(); }

    const char* tile_base = cb_sw + (size_t)blockIdx.y * NTILES * TILE_BYTES;
    auto stage = [&](int buf, int t) {
        const char* src = tile_base + (size_t)t * TILE_BYTES;
        char* dst = &Bls[buf][0][0];
#pragma unroll
        for (int j = 0; j < 4; ++j)
            gload_lds16(src + j * 8192 + tid * 16, dst + j * 8192 + tid * 16);
    };

#define CHUNK_BODY(T_IDX, CH, TRACK, EMIT)                                      \
    {                                                                           \
        const char* B0 = &Bls[(T_IDX) & 1][0][0];                               \
        const char* B1 = &Bls[(T_IDX) & 1][1][0];                               \
        const int colLocal = (CH) * 16 + l15;                                   \
        unsigned off0 = swz(colLocal, lhi * 16);                                \
        unsigned off1 = swz(colLocal, 64 + lhi * 16);                           \
        bf16x8 br0 = *(const bf16x8*)(B0 + off0);                               \
        bf16x8 bi0 = *(const bf16x8*)(B1 + off0);                               \
        bf16x8 br1 = *(const bf16x8*)(B0 + off1);                               \
        bf16x8 bi1 = *(const bf16x8*)(B1 + off1);                               \
        f32x4 accre[2], accim[2];                                               \
        _Pragma("unroll")                                                       \
        for (int a = 0; a < 2; ++a) {                                           \
            accre[a] = (f32x4){0.f, 0.f, 0.f, 0.f};                             \
            accim[a] = (f32x4){0.f, 0.f, 0.f, 0.f};                             \
        }                                                                       \
        _Pragma("unroll")                                                       \
        for (int a = 0; a < 2; ++a) {                                           \
            accre[a] = __builtin_amdgcn_mfma_f32_16x16x32_bf16(Ar[a][0], br0, accre[a], 0, 0, 0); \
            accre[a] = __builtin_amdgcn_mfma_f32_16x16x32_bf16(Ai[a][0], bi0, accre[a], 0, 0, 0); \
            accre[a] = __builtin_amdgcn_mfma_f32_16x16x32_bf16(Ar[a][1], br1, accre[a], 0, 0, 0); \
            accre[a] = __builtin_amdgcn_mfma_f32_16x16x32_bf16(Ai[a][1], bi1, accre[a], 0, 0, 0); \
            accim[a] = __builtin_amdgcn_mfma_f32_16x16x32_bf16(Ar[a][0], bi0, accim[a], 0, 0, 0); \
            accim[a] = __builtin_amdgcn_mfma_f32_16x16x32_bf16(Ar[a][1], bi1, accim[a], 0, 0, 0); \
        }                                                                       \
        br0 = br0 ^ (short)0x8000;                                              \
        br1 = br1 ^ (short)0x8000;                                              \
        _Pragma("unroll")                                                       \
        for (int a = 0; a < 2; ++a) {                                           \
            accim[a] = __builtin_amdgcn_mfma_f32_16x16x32_bf16(Ai[a][0], br0, accim[a], 0, 0, 0); \
            accim[a] = __builtin_amdgcn_mfma_f32_16x16x32_bf16(Ai[a][1], br1, accim[a], 0, 0, 0); \
        }                                                                       \
        _Pragma("unroll")                                                       \
        for (int a = 0; a < 2; ++a)                                             \
            _Pragma("unroll")                                                   \
            for (int r = 0; r < 4; ++r) {                                       \
                float re = accre[a][r], im = accim[a][r];                       \
                float m2 = fmaf(re, re, im * im);                               \
                if (TRACK) rm[a][r] = fmaxf(rm[a][r], m2);                      \
                if (EMIT) {                                                     \
                    if (m2 >= thr[a][r]) {                                      \
                        int nl = wid * 32 + a * 16 + lhi * 4 + r;               \
                        int k  = col0 + (T_IDX) * TILE_COLS + (CH) * 16 + l15;  \
                        int idx = atomicAdd(&cand_cnt, 1);                      \
                        if (idx < CAP) cand[idx] = ((unsigned)nl << 14) | (unsigned)k; \
                        else flags[bid] = 1;   /* cold: rescue kernel redoes block */ \
                    }                                                           \
                }                                                               \
            }                                                                   \
    }

#define FOLD_SMAX()                                                             \
    {                                                                           \
        _Pragma("unroll")                                                       \
        for (int m = 1; m < 16; m <<= 1)                                        \
            _Pragma("unroll")                                                   \
            for (int a = 0; a < 2; ++a)                                         \
                _Pragma("unroll")                                               \
                for (int r = 0; r < 4; ++r)                                     \
                    rm[a][r] = fmaxf(rm[a][r], __shfl_xor(rm[a][r], m, 64));    \
        if (l15 == 0) {                                                         \
            _Pragma("unroll")                                                   \
            for (int a = 0; a < 2; ++a)                                         \
                _Pragma("unroll")                                               \
                for (int r = 0; r < 4; ++r)                                     \
                    atomicMax(&smax[wid * 32 + a * 16 + lhi * 4 + r],           \
                              __float_as_uint(rm[a][r]));                       \
        }                                                                       \
    }

#define LOAD_THR()                                                              \
    {                                                                           \
        _Pragma("unroll")                                                       \
        for (int a = 0; a < 2; ++a)                                             \
            _Pragma("unroll")                                                   \
            for (int r = 0; r < 4; ++r) {                                       \
                float mx = __uint_as_float(smax[wid * 32 + a * 16 + lhi * 4 + r]); \
                float tm = sqrtf(mx) - DELTA;                                   \
                thr[a][r] = (tm > 0.0f) ? tm * tm : -1.0f;                      \
            }                                                                   \
    }

    stage(0, 0);
    __syncthreads();   // drains tile-0 loads; smax/cand_cnt init visible

    for (int t = 0; t < NTILES; ++t) {
        stage((t + 1) & 1, (t + 1) & 15);   // t=15 restages tile 0 for replay
        asm volatile("s_waitcnt vmcnt(4)" ::: "memory");
        __builtin_amdgcn_sched_barrier(0);
        __builtin_amdgcn_s_barrier();
        __builtin_amdgcn_sched_barrier(0);

        if (t >= 2) {
            LOAD_THR()
            for (int ch = 0; ch < NCHUNK; ++ch)
                CHUNK_BODY(t, ch, 1, 1)
        } else {
            // tiles 0,1: max-tracking only (thresholds too loose) — replayed below
            for (int ch = 0; ch < NCHUNK; ++ch)
                CHUNK_BODY(t, ch, 1, 0)
        }
        FOLD_SMAX()

        __builtin_amdgcn_sched_barrier(0);
        __builtin_amdgcn_s_barrier();   // compute done, emissions visible

        // ---- uniform mid-loop drain (cold path, REGISTER-LIGHT rescore) ----
        int dc = cand_cnt;
        if (dc > DRAIN_AT) {
            int m = dc < CAP ? dc : CAP;
            for (int i = tid; i < m; i += 512) {
                unsigned e = cand[i];
                rescore_lean(row0 + (int)(e >> 14), (int)(e & 16383u),
                             x_re, x_im, cb_re, cb_im, best_packed);
            }
            __builtin_amdgcn_s_barrier();
            if (tid == 0) cand_cnt = 0;
            __builtin_amdgcn_s_barrier();
        }
    }

    // ---- tail: restage tile 1, replay tiles 0 & 1 emission-only ----
    stage(1, 1);                       // buf1 <- tile 1 (buf0 holds tile 0)
    asm volatile("s_waitcnt vmcnt(0)" ::: "memory");
    __builtin_amdgcn_sched_barrier(0);
    __builtin_amdgcn_s_barrier();
    __builtin_amdgcn_sched_barrier(0);
    LOAD_THR()
    for (int ch = 0; ch < NCHUNK; ++ch)
        CHUNK_BODY(0, ch, 0, 1)
    for (int ch = 0; ch < NCHUNK; ++ch)
        CHUNK_BODY(1, ch, 0, 1)

    __syncthreads();   // cand list final

#undef CHUNK_BODY
#undef FOLD_SMAX
#undef LOAD_THR

    // ---- final drain: fast float4 rescore (A-frags dead here — r6-proven) ----
    int cnt = cand_cnt < CAP ? cand_cnt : CAP;
    for (int i = tid; i < cnt; i += 512) {
        unsigned e = cand[i];
        rescore_fast(row0 + (int)(e >> 14), (int)(e & 16383u),
                     x_re, x_im, cb_re, cb_im, best_packed);
    }
}

// rescue: exact rescan of any block whose LDS list overflowed (≈never)
__global__ __launch_bounds__(512) void rescue(
    const float* __restrict__ x_re, const float* __restrict__ x_im,
    const float* __restrict__ cb_re, const float* __restrict__ cb_im,
    const int* __restrict__ flags,
    unsigned long long* __restrict__ best_packed)
{
    const int bid = blockIdx.x;            // 0..511, matches score's bid
    if (flags[bid] == 0) return;
    const int row0 = (bid & 63) * BM;
    const int col0 = (bid >> 6) * COLS_PER_BLOCK;
    for (int i = threadIdx.x; i < BM * COLS_PER_BLOCK; i += 512)
        rescore_fast(row0 + (i >> 11), col0 + (i & 2047),
                     x_re, x_im, cb_re, cb_im, best_packed);
}

__global__ __launch_bounds__(256) void finalize(
    const unsigned long long* __restrict__ best_packed,
    const float* __restrict__ cb_re, const float* __restrict__ cb_im,
    float* __restrict__ out)
{
    const int wave = threadIdx.x >> 6;
    const int lane = threadIdx.x & 63;
    const int n = blockIdx.x * 4 + wave;
    if (n >= NROWS) return;

    unsigned long long p = best_packed[n];
    unsigned k = ~(unsigned)(p & 0xFFFFFFFFull);

    if (lane == 0) out[n] = (float)k;

    float re = cb_re[(size_t)k * DD + lane];
    float im = cb_im[(size_t)k * DD + lane];
    float2* ro = reinterpret_cast<float2*>(out + NROWS);
    ro[(size_t)n * DD + lane] = make_float2(re, im);
}

extern "C" void kernel_launch(void* const* d_in, const int* in_sizes, int n_in,
                              void* d_out, int out_size, void* d_ws, size_t ws_size,
                              hipStream_t stream)
{
    const float* x_re  = (const float*)d_in[0];
    const float* x_im  = (const float*)d_in[1];
    const float* cb_re = (const float*)d_in[2];
    const float* cb_im = (const float*)d_in[3];
    float* out = (float*)d_out;

    const size_t CB_SW_BYTES = (size_t)(KCB / TILE_COLS) * TILE_BYTES;   // 4 MB
    char* p = (char*)d_ws;
    const char* cb_sw = p;                                        p += CB_SW_BYTES;
    unsigned long long* best_packed = (unsigned long long*)p;     p += (size_t)NROWS * 8;
    int* flags = (int*)p;

    prep<<<1024, 256, 0, stream>>>(cb_re, cb_im, (uint4*)d_ws, best_packed, flags);

    dim3 grid(NROWS / BM, CSPLIT);
    score_kernel<<<grid, 512, 0, stream>>>(x_re, x_im, cb_re, cb_im,
                                           cb_sw, best_packed, flags);

    rescue<<<512, 512, 0, stream>>>(x_re, x_im, cb_re, cb_im, flags, best_packed);

    finalize<<<NROWS / 4, 256, 0, stream>>>(best_packed, cb_re, cb_im, out);
}

// Round 11
// 295.831 us; speedup vs baseline: 2.8826x; 2.8826x over previous
//
#include <hip/hip_runtime.h>

#define NROWS 16384
#define KCB   16384
#define DD    64
#define BM    256
#define CSPLIT 16
#define COLS_PER_BLOCK 1024
#define TILE_COLS 128
#define NTILES (COLS_PER_BLOCK / TILE_COLS)   // 8
#define NCHUNK (TILE_COLS / 16)               // 8
#define CAP 2048
#define DELTA 0.45f
#define TILE_BYTES 32768                      // [re 16KB][im 16KB] per 128-col tile

typedef __attribute__((ext_vector_type(8))) short bf16x8;
typedef __attribute__((ext_vector_type(4))) float f32x4;
typedef __attribute__((ext_vector_type(2))) float f32x2;

__device__ __forceinline__ unsigned pk_bf16(float lo, float hi) {
    unsigned a = __float_as_uint(lo);
    unsigned b = __float_as_uint(hi);
    a += 0x7FFFu + ((a >> 16) & 1u);   // RNE to bf16
    b += 0x7FFFu + ((b >> 16) & 1u);
    return (a >> 16) | (b & 0xFFFF0000u);
}

__device__ __forceinline__ bf16x8 mk8(unsigned a, unsigned b, unsigned c, unsigned d) {
    union { uint4 u; bf16x8 v; } x;
    x.u = make_uint4(a, b, c, d);
    return x.v;
}

__device__ __forceinline__ f32x2 lo2(f32x4 v) { return __builtin_shufflevector(v, v, 0, 1); }
__device__ __forceinline__ f32x2 hi2(f32x4 v) { return __builtin_shufflevector(v, v, 2, 3); }

// XOR swizzle within 128B rows: 16 lanes -> 8 bank-slots = 2-way (free)
__device__ __forceinline__ unsigned swz(unsigned row, unsigned byte_in_row) {
    return row * 128u + (byte_in_row ^ ((row & 7u) << 4));
}

__device__ __forceinline__ void gload_lds16(const void* g, void* l) {
    __builtin_amdgcn_global_load_lds(
        (__attribute__((address_space(1))) void*)(g),
        (__attribute__((address_space(3))) void*)(l), 16, 0, 0);
}

// exact fp32 rescore, round-1 FMA order (absmax-0 proven); used only OUTSIDE
// the MFMA t-loop (r6-proven placement: no interaction with A-frag live range)
__device__ __forceinline__ void rescore_fast(
    int n, int k,
    const float* __restrict__ x_re, const float* __restrict__ x_im,
    const float* __restrict__ cb_re, const float* __restrict__ cb_im,
    unsigned long long* __restrict__ best_packed)
{
    const float4* xr = (const float4*)(x_re + (size_t)n * DD);
    const float4* xi = (const float4*)(x_im + (size_t)n * DD);
    const float4* cr = (const float4*)(cb_re + (size_t)k * DD);
    const float4* ci = (const float4*)(cb_im + (size_t)k * DD);
    float accr = 0.0f, acci = 0.0f;
#pragma unroll 4
    for (int d4 = 0; d4 < 16; ++d4) {
        float4 a = xr[d4], b = xi[d4], c = cr[d4], e = ci[d4];
        accr = fmaf(a.x, c.x, accr); accr = fmaf(b.x, e.x, accr);
        acci = fmaf(a.x, e.x, acci); acci = fmaf(-b.x, c.x, acci);
        accr = fmaf(a.y, c.y, accr); accr = fmaf(b.y, e.y, accr);
        acci = fmaf(a.y, e.y, acci); acci = fmaf(-b.y, c.y, acci);
        accr = fmaf(a.z, c.z, accr); accr = fmaf(b.z, e.z, accr);
        acci = fmaf(a.z, e.z, acci); acci = fmaf(-b.z, c.z, acci);
        accr = fmaf(a.w, c.w, accr); accr = fmaf(b.w, e.w, accr);
        acci = fmaf(a.w, e.w, acci); acci = fmaf(-b.w, c.w, acci);
    }
    float m2 = accr * accr + acci * acci;
    unsigned long long key =
        ((unsigned long long)__float_as_uint(m2) << 32) | (unsigned)(~(unsigned)k);
    atomicMax(best_packed + n, key);
}

// prep: init reductions + flags; convert codebook fp32 -> bf16 in
// INVERSE-SWIZZLED tile order (linear global_load_lds dest -> swizzled reads).
__global__ __launch_bounds__(256) void prep(
    const float* __restrict__ cb_re, const float* __restrict__ cb_im,
    uint4* __restrict__ cb_sw,
    unsigned* __restrict__ row_max_bits,
    unsigned long long* __restrict__ best_packed, int* __restrict__ flags)
{
    int id = blockIdx.x * 256 + threadIdx.x;
    if (id < NROWS) { row_max_bits[id] = 0u; best_packed[id] = 0ull; }
    if (id < 1024) flags[id] = 0;
    // id in [0, 262144): [gt 0..127][arr 0..1][u 0..1023], one uint4 (16B) each
    int u   = id & 1023;
    int arr = (id >> 10) & 1;
    int gt  = id >> 11;
    int c   = u >> 3;                                  // col within tile
    int b   = ((u & 7) * 16) ^ ((c & 7) << 4);         // inverse-swizzled byte
    int col = gt * TILE_COLS + c;
    int d0  = b >> 1;                                  // bf16 element index (8-aligned)
    const float* src = arr ? cb_im : cb_re;
    const float4* p = (const float4*)(src + (size_t)col * DD + d0);
    float4 f0 = p[0], f1 = p[1];
    cb_sw[id] = make_uint4(pk_bf16(f0.x, f0.y), pk_bf16(f0.z, f0.w),
                           pk_bf16(f1.x, f1.y), pk_bf16(f1.z, f1.w));
}

template<int PASS>
__global__ __launch_bounds__(512, 2) void score_kernel(
    const float* __restrict__ x_re, const float* __restrict__ x_im,
    const float* __restrict__ cb_re, const float* __restrict__ cb_im,
    const char* __restrict__ cb_sw,
    unsigned* __restrict__ row_max_bits,
    unsigned long long* __restrict__ best_packed, int* __restrict__ flags)
{
    __shared__ char Bls[2][2][TILE_COLS * 128];   // 64 KB
    __shared__ unsigned cand[CAP];                // 8 KB
    __shared__ int cand_cnt;

    const int tid  = threadIdx.x;
    const int lane = tid & 63;
    const int wid  = tid >> 6;          // 0..7 = row-group of 32
    const int row0 = blockIdx.x * BM;
    const int col0 = blockIdx.y * COLS_PER_BLOCK;
    const int bid  = blockIdx.y * gridDim.x + blockIdx.x;   // < 1024
    const int l15  = lane & 15;
    const int lhi  = lane >> 4;         // 0..3

    if (tid == 0) cand_cnt = 0;

    // ---- A fragments: 32 rows/wave, {re, im, -im}, built once in registers ----
    bf16x8 Ar[2][2], Ai[2][2], Ain[2][2];
#pragma unroll
    for (int a = 0; a < 2; ++a) {
        const int row = row0 + wid * 32 + a * 16 + l15;
#pragma unroll
        for (int ks = 0; ks < 2; ++ks) {
            const float4* pr = (const float4*)(x_re + (size_t)row * DD + ks * 32 + lhi * 8);
            const float4* pi = (const float4*)(x_im + (size_t)row * DD + ks * 32 + lhi * 8);
            float4 r0 = pr[0], r1 = pr[1];
            float4 i0 = pi[0], i1 = pi[1];
            Ar[a][ks] = mk8(pk_bf16(r0.x, r0.y), pk_bf16(r0.z, r0.w),
                            pk_bf16(r1.x, r1.y), pk_bf16(r1.z, r1.w));
            Ai[a][ks] = mk8(pk_bf16(i0.x, i0.y), pk_bf16(i0.z, i0.w),
                            pk_bf16(i1.x, i1.y), pk_bf16(i1.z, i1.w));
            Ain[a][ks] = Ai[a][ks] ^ (short)0x8000;   // exact bf16 negation
        }
    }

    // loop-invariant zero C operand: first MFMA of each chain reads FZERO,
    // so no per-chunk accumulator zero-init movs are needed.
    const f32x4 FZERO = (f32x4){0.f, 0.f, 0.f, 0.f};

    f32x2 rm2[2][2];                   // pass1 running max, packed pairs (r0,r1)(r2,r3)
    f32x2 thr2[2][2];                  // pass2 thresholds, same packing
#pragma unroll
    for (int a = 0; a < 2; ++a)
#pragma unroll
        for (int j = 0; j < 2; ++j) rm2[a][j] = (f32x2){0.f, 0.f};
    if (PASS == 2) {
#pragma unroll
        for (int a = 0; a < 2; ++a)
#pragma unroll
            for (int j = 0; j < 2; ++j) {
#pragma unroll
                for (int h = 0; h < 2; ++h) {
                    int n = row0 + wid * 32 + a * 16 + lhi * 4 + j * 2 + h;
                    float mx = __uint_as_float(row_max_bits[n]);
                    float tm = sqrtf(mx) - DELTA;
                    thr2[a][j][h] = (tm > 0.0f) ? tm * tm : -1.0f;
                }
            }
    }

    bool ovf = false;                  // register-only overflow flag (no hot-loop stores)

    const char* tile_base = cb_sw + (size_t)blockIdx.y * NTILES * TILE_BYTES;
    auto stage = [&](int buf, int t) {
        const char* src = tile_base + (size_t)t * TILE_BYTES;
        char* dst = &Bls[buf][0][0];
#pragma unroll
        for (int j = 0; j < 4; ++j)
            gload_lds16(src + j * 8192 + tid * 16, dst + j * 8192 + tid * 16);
    };

    stage(0, 0);
    __syncthreads();   // drain tile-0 loads + cand_cnt init visible

    for (int t = 0; t < NTILES; ++t) {
        const int cur = t & 1;
        if (t + 1 < NTILES) {
            stage(cur ^ 1, t + 1);                            // 4 loads in flight
            asm volatile("s_waitcnt vmcnt(4)" ::: "memory");  // tile t done
        } else {
            asm volatile("s_waitcnt vmcnt(0)" ::: "memory");
        }
        __builtin_amdgcn_sched_barrier(0);
        __builtin_amdgcn_s_barrier();
        __builtin_amdgcn_sched_barrier(0);

        for (int ch = 0; ch < NCHUNK; ++ch) {
            const char* B0 = &Bls[cur][0][0];
            const char* B1 = &Bls[cur][1][0];
            const int colLocal = ch * 16 + l15;
            unsigned off0 = swz(colLocal, lhi * 16);
            unsigned off1 = swz(colLocal, 64 + lhi * 16);
            bf16x8 br0 = *(const bf16x8*)(B0 + off0);
            bf16x8 bi0 = *(const bf16x8*)(B1 + off0);
            bf16x8 br1 = *(const bf16x8*)(B0 + off1);
            bf16x8 bi1 = *(const bf16x8*)(B1 + off1);

            f32x4 accre[2], accim[2];
#pragma unroll
            for (int a = 0; a < 2; ++a) {
                accre[a] = __builtin_amdgcn_mfma_f32_16x16x32_bf16(Ar[a][0], br0, FZERO, 0, 0, 0);
                accre[a] = __builtin_amdgcn_mfma_f32_16x16x32_bf16(Ai[a][0], bi0, accre[a], 0, 0, 0);
                accre[a] = __builtin_amdgcn_mfma_f32_16x16x32_bf16(Ar[a][1], br1, accre[a], 0, 0, 0);
                accre[a] = __builtin_amdgcn_mfma_f32_16x16x32_bf16(Ai[a][1], bi1, accre[a], 0, 0, 0);
                accim[a] = __builtin_amdgcn_mfma_f32_16x16x32_bf16(Ar[a][0], bi0, FZERO, 0, 0, 0);
                accim[a] = __builtin_amdgcn_mfma_f32_16x16x32_bf16(Ain[a][0], br0, accim[a], 0, 0, 0);
                accim[a] = __builtin_amdgcn_mfma_f32_16x16x32_bf16(Ar[a][1], bi1, accim[a], 0, 0, 0);
                accim[a] = __builtin_amdgcn_mfma_f32_16x16x32_bf16(Ain[a][1], br1, accim[a], 0, 0, 0);
            }

            // packed epilogue: v_pk_mul / v_pk_fma on f32x2 pairs
#pragma unroll
            for (int a = 0; a < 2; ++a) {
                f32x2 m2p[2];
                {
                    f32x2 rl = lo2(accre[a]), il = lo2(accim[a]);
                    f32x2 rh = hi2(accre[a]), ih = hi2(accim[a]);
                    m2p[0] = rl * rl + il * il;
                    m2p[1] = rh * rh + ih * ih;
                }
                if (PASS == 1) {
#pragma unroll
                    for (int j = 0; j < 2; ++j)
                        rm2[a][j] = __builtin_elementwise_max(rm2[a][j], m2p[j]);
                } else {
#pragma unroll
                    for (int j = 0; j < 2; ++j)
#pragma unroll
                        for (int h = 0; h < 2; ++h) {
                            if (m2p[j][h] >= thr2[a][j][h]) {
                                int nl = wid * 32 + a * 16 + lhi * 4 + j * 2 + h;
                                int k  = col0 + t * TILE_COLS + ch * 16 + l15;
                                int idx = atomicAdd(&cand_cnt, 1);
                                if (idx < CAP) cand[idx] = ((unsigned)nl << 14) | (unsigned)k;
                                else ovf = true;   // register flag only
                            }
                        }
                }
            }
        }

        __builtin_amdgcn_sched_barrier(0);
        __builtin_amdgcn_s_barrier();   // all waves done reading buf before overwrite
    }
    __syncthreads();

    if (PASS == 1) {
        // unpack, fold max over the 16 col-lanes, then global atomicMax per row
#pragma unroll
        for (int a = 0; a < 2; ++a)
#pragma unroll
            for (int j = 0; j < 2; ++j)
#pragma unroll
                for (int h = 0; h < 2; ++h) {
                    float v = rm2[a][j][h];
#pragma unroll
                    for (int m = 1; m < 16; m <<= 1)
                        v = fmaxf(v, __shfl_xor(v, m, 64));
                    if (l15 == 0) {
                        int n = row0 + wid * 32 + a * 16 + lhi * 4 + j * 2 + h;
                        atomicMax(&row_max_bits[n], __float_as_uint(v));
                    }
                }
    } else {
        if (ovf) flags[bid] = 1;       // cold, once, after the loop
        // exact fp32 rescore of surviving candidates (A-frags dead here)
        int cnt = cand_cnt < CAP ? cand_cnt : CAP;
        for (int i = tid; i < cnt; i += 512) {
            unsigned e = cand[i];
            rescore_fast(row0 + (int)(e >> 14), (int)(e & 16383u),
                         x_re, x_im, cb_re, cb_im, best_packed);
        }
    }
}

// rescue: exact rescan of any block whose LDS list overflowed (≈never)
__global__ __launch_bounds__(512) void rescue(
    const float* __restrict__ x_re, const float* __restrict__ x_im,
    const float* __restrict__ cb_re, const float* __restrict__ cb_im,
    const int* __restrict__ flags,
    unsigned long long* __restrict__ best_packed)
{
    const int bid = blockIdx.x;            // 0..1023, matches score's bid
    if (flags[bid] == 0) return;
    const int row0 = (bid & 63) * BM;
    const int col0 = (bid >> 6) * COLS_PER_BLOCK;
    for (int i = threadIdx.x; i < BM * COLS_PER_BLOCK; i += 512)
        rescore_fast(row0 + (i >> 10), col0 + (i & 1023),
                     x_re, x_im, cb_re, cb_im, best_packed);
}

__global__ __launch_bounds__(256) void finalize(
    const unsigned long long* __restrict__ best_packed,
    const float* __restrict__ cb_re, const float* __restrict__ cb_im,
    float* __restrict__ out)
{
    const int wave = threadIdx.x >> 6;
    const int lane = threadIdx.x & 63;
    const int n = blockIdx.x * 4 + wave;
    if (n >= NROWS) return;

    unsigned long long p = best_packed[n];
    unsigned k = ~(unsigned)(p & 0xFFFFFFFFull);

    if (lane == 0) out[n] = (float)k;

    float re = cb_re[(size_t)k * DD + lane];
    float im = cb_im[(size_t)k * DD + lane];
    float2* ro = reinterpret_cast<float2*>(out + NROWS);
    ro[(size_t)n * DD + lane] = make_float2(re, im);
}

extern "C" void kernel_launch(void* const* d_in, const int* in_sizes, int n_in,
                              void* d_out, int out_size, void* d_ws, size_t ws_size,
                              hipStream_t stream)
{
    const float* x_re  = (const float*)d_in[0];
    const float* x_im  = (const float*)d_in[1];
    const float* cb_re = (const float*)d_in[2];
    const float* cb_im = (const float*)d_in[3];
    float* out = (float*)d_out;

    const size_t CB_SW_BYTES = (size_t)(KCB / TILE_COLS) * TILE_BYTES;   // 4 MB
    char* p = (char*)d_ws;
    const char* cb_sw = p;                                        p += CB_SW_BYTES;
    unsigned long long* best_packed = (unsigned long long*)p;     p += (size_t)NROWS * 8;
    unsigned* row_max_bits = (unsigned*)p;                        p += (size_t)NROWS * 4;
    int* flags = (int*)p;

    prep<<<1024, 256, 0, stream>>>(cb_re, cb_im, (uint4*)d_ws,
                                   row_max_bits, best_packed, flags);

    dim3 grid(NROWS / BM, CSPLIT);
    score_kernel<1><<<grid, 512, 0, stream>>>(x_re, x_im, cb_re, cb_im, cb_sw,
                                              row_max_bits, best_packed, flags);
    score_kernel<2><<<grid, 512, 0, stream>>>(x_re, x_im, cb_re, cb_im, cb_sw,
                                              row_max_bits, best_packed, flags);

    rescue<<<1024, 512, 0, stream>>>(x_re, x_im, cb_re, cb_im, flags, best_packed);

    finalize<<<NROWS / 4, 256, 0, stream>>>(best_packed, cb_re, cb_im, out);
}